// Round 5
// baseline (133.532 us; speedup 1.0000x reference)
//
#include <hip/hip_runtime.h>

#define B        4
#define N        16384       // 2^14
#define NPOINT   2048        // 2^11
#define C        64
#define NSAMPLE  32
#define CH       (C + 3)     // 67 output channels
#define RADIUS2  0.01f
#define NCELL    1000        // 10^3 cells per batch (cell size = radius)
#define CSTRIDE  1032        // cell_start row stride (ints) >= NCELL+1
#define CCSTRIDE 1024        // counter row stride (ints)
#define CAP      192         // per-query candidate cap (mean ~68, ~15 sigma)

typedef float vfloat4 __attribute__((ext_vector_type(4)));  // for nontemporal

__device__ __forceinline__ int clamp10(int v) {
    return v < 0 ? 0 : (v > 9 ? 9 : v);
}

// ---------------------------------------------------------------------------
// Transpose features (B,C,N) -> (B,N,C), float4 both directions.
// Also zeros the per-cell counters cc (ws is poisoned before every call).
// grid = (N/64, B), block = 256
// ---------------------------------------------------------------------------
__global__ __launch_bounds__(256) void feat_transpose_zero_kernel(
    const float* __restrict__ f,   // (B,C,N)
    float* __restrict__ ft,        // (B,N,C)
    int* __restrict__ cc)          // B*CCSTRIDE counters -> 0
{
    if (blockIdx.y == 0 && blockIdx.x < (B * CCSTRIDE) / 256)
        cc[blockIdx.x * 256 + threadIdx.x] = 0;

    __shared__ float tile[64][65];
    const int b  = blockIdx.y;
    const int n0 = blockIdx.x * 64;
    const int t  = threadIdx.x;
    const int r16 = t >> 4;                  // 0..15
    const int x4  = t & 15;                  // 0..15
    #pragma unroll
    for (int it = 0; it < 4; ++it) {
        const int cc_ = it * 16 + r16;
        const float4 v = *(const float4*)(f + ((size_t)b * C + cc_) * N + n0 + x4 * 4);
        tile[cc_][x4 * 4 + 0] = v.x;
        tile[cc_][x4 * 4 + 1] = v.y;
        tile[cc_][x4 * 4 + 2] = v.z;
        tile[cc_][x4 * 4 + 3] = v.w;
    }
    __syncthreads();
    #pragma unroll
    for (int it = 0; it < 4; ++it) {
        const int nn = it * 16 + r16;
        float4 v;
        v.x = tile[x4 * 4 + 0][nn];
        v.y = tile[x4 * 4 + 1][nn];
        v.z = tile[x4 * 4 + 2][nn];
        v.w = tile[x4 * 4 + 3][nn];
        *(float4*)(ft + ((size_t)b * N + n0 + nn) * C + x4 * 4) = v;
    }
}

// ---------------------------------------------------------------------------
// Grid build: count points per cell (global atomics, 256 blocks).
// ---------------------------------------------------------------------------
__global__ __launch_bounds__(256) void count_kernel(const float* __restrict__ xyz,
                                                    int* __restrict__ cnt) {
    const int g = blockIdx.x * 256 + threadIdx.x;   // < B*N
    const int b = g >> 14;
    const float x = xyz[g * 3 + 0], y = xyz[g * 3 + 1], z = xyz[g * 3 + 2];
    const int cx = clamp10((int)(x * 10.f));
    const int cy = clamp10((int)(y * 10.f));
    const int cz = clamp10((int)(z * 10.f));
    atomicAdd(&cnt[(b << 10) + (cx * 10 + cy) * 10 + cz], 1);
}

// ---------------------------------------------------------------------------
// Grid build: exclusive scan (1000 cells/batch). grid = B, block = 1024.
// Writes cell_start[0..1000]; re-inits cnt[] as the scatter cursor.
// ---------------------------------------------------------------------------
__global__ __launch_bounds__(1024) void prefix_kernel(int* __restrict__ cnt,
                                                      int* __restrict__ cs) {
    __shared__ int s[1024];
    const int t = threadIdx.x, b = blockIdx.x;
    const int v = (t < NCELL) ? cnt[(b << 10) + t] : 0;
    s[t] = v;
    __syncthreads();
    for (int off = 1; off < 1024; off <<= 1) {
        const int u = (t >= off) ? s[t - off] : 0;
        __syncthreads();
        s[t] += u;
        __syncthreads();
    }
    const int excl = (t == 0) ? 0 : s[t - 1];
    if (t <= NCELL) cs[b * CSTRIDE + t] = excl;
    if (t < NCELL)  cnt[(b << 10) + t] = excl;
}

// ---------------------------------------------------------------------------
// Grid build: scatter points to cell-sorted float4(x,y,z,bitcast(index)).
// ---------------------------------------------------------------------------
__global__ __launch_bounds__(256) void scatter_kernel(const float* __restrict__ xyz,
                                                      int* __restrict__ cursor,
                                                      float4* __restrict__ sp) {
    const int g = blockIdx.x * 256 + threadIdx.x;
    const int b = g >> 14;
    const int n = g & (N - 1);
    const float x = xyz[g * 3 + 0], y = xyz[g * 3 + 1], z = xyz[g * 3 + 2];
    const int cx = clamp10((int)(x * 10.f));
    const int cy = clamp10((int)(y * 10.f));
    const int cz = clamp10((int)(z * 10.f));
    const int cell = (cx * 10 + cy) * 10 + cz;
    const int pos = atomicAdd(&cursor[(b << 10) + cell], 1);
    sp[(b << 14) + pos] = make_float4(x, y, z, __int_as_float(n));
}

// ---------------------------------------------------------------------------
// Ball query. One wave per query, 4 queries per 256-thr block.
// launch_bounds(256,8): VGPR<=64 -> 8 blocks/CU = 32 waves/CU.
// Order-free flattened scan of the 9 z-runs (rank-select restores index
// order afterwards). Run bounds hoisted to SGPRs via readlane. All LDS is
// wave-private -> __threadfence_block() instead of barriers.
// Outputs: cnt (float, to d_out) and idx lists (int, to ws).
// ---------------------------------------------------------------------------
__global__ __launch_bounds__(256, 8) void ballquery_kernel(
    const float*  __restrict__ xyz,      // (B,N,3) (overflow fallback only)
    const float*  __restrict__ new_xyz,  // (B,NPOINT,3)
    const int*    __restrict__ cs,       // cell_start
    const float4* __restrict__ sp,       // cell-sorted points
    float* __restrict__ out_cnt,         // B*NPOINT
    int*   __restrict__ idx_out)         // (B*NPOINT, NSAMPLE)
{
    const int w = threadIdx.x >> 6;      // wave 0..3
    const int l = threadIdx.x & 63;
    const int q = blockIdx.x * 4 + w;    // 0..B*NPOINT-1
    const int b = q >> 11;

    __shared__ int cand_s[4][CAP];
    __shared__ int sidx_s[4][NSAMPLE];
    int* cand  = cand_s[w];
    int* s_idx = sidx_s[w];

    const float qx = new_xyz[q * 3 + 0];
    const float qy = new_xyz[q * 3 + 1];
    const float qz = new_xyz[q * 3 + 2];

    const int cx = clamp10((int)(qx * 10.f));
    const int cy = clamp10((int)(qy * 10.f));
    const int cz = clamp10((int)(qz * 10.f));
    const int z0 = cz > 0 ? cz - 1 : 0;
    const int z1 = cz < 9 ? cz + 1 : 9;

    // lanes 0..8 fetch the 9 run bounds (3x3 xy-cells, z contiguous)
    int sv = 0, ev = 0;
    if (l < 9) {
        const int xx = cx - 1 + l / 3;
        const int yy = cy - 1 + l % 3;
        if (xx >= 0 && xx <= 9 && yy >= 0 && yy <= 9) {
            const int cb = (xx * 10 + yy) * 10;
            sv = cs[b * CSTRIDE + cb + z0];
            ev = cs[b * CSTRIDE + cb + z1 + 1];
        }
    }
    const int len = ev - sv;

    // hoist run starts/lengths into uniform (SGPR) values
    int S[9], L[9];
    #pragma unroll
    for (int r = 0; r < 9; ++r) {
        S[r] = __builtin_amdgcn_readlane(sv, r);
        L[r] = __builtin_amdgcn_readlane(len, r);
    }
    int T = 0;
    #pragma unroll
    for (int r = 0; r < 9; ++r) T += L[r];

    const unsigned long long ltmask = (1ull << l) - 1ull;
    int total = 0, ncand = 0;
    for (int base = 0; base < T; base += 64) {
        const int wid = base + l;
        // select run + position for this work item (unrolled, register-only)
        int p = 0, acc = 0;
        bool act = false;
        #pragma unroll
        for (int r = 0; r < 9; ++r) {
            const int off = wid - acc;
            if (off >= 0 && off < L[r]) { p = S[r] + off; act = true; }
            acc += L[r];
        }
        float4 pt = make_float4(1e9f, 1e9f, 1e9f, 0.f);
        if (act) pt = sp[(b << 14) + p];
        const float dx = pt.x - qx, dy = pt.y - qy, dz = pt.z - qz;
        const float d2 = dx * dx + dy * dy + dz * dz;
        const bool in = act && (d2 < RADIUS2);
        const unsigned long long m = __ballot(in);
        if (in) {
            const int slot = ncand + __popcll(m & ltmask);
            if (slot < CAP) cand[slot] = __float_as_int(pt.w);
        }
        const int c = __popcll(m);
        total += c;
        ncand = ncand + c > CAP ? CAP : ncand + c;
    }

    int cntv;
    if (total > CAP) {
        // overflow (astronomically unlikely for uniform data): ordered rescan
        const float* xb = xyz + (size_t)b * N * 3;
        int cnt2 = 0;
        for (int base = 0; base < N; base += 64) {
            const int p = base + l;
            const float dx = xb[p * 3 + 0] - qx;
            const float dy = xb[p * 3 + 1] - qy;
            const float dz = xb[p * 3 + 2] - qz;
            const float d2 = dx * dx + dy * dy + dz * dz;
            const bool in = d2 < RADIUS2;
            const unsigned long long m = __ballot(in);
            if (in) {
                const int slot = cnt2 + __popcll(m & ltmask);
                if (slot < NSAMPLE) s_idx[slot] = p;
            }
            cnt2 += __popcll(m);
            if (cnt2 >= NSAMPLE) break;
        }
        cntv = cnt2 < NSAMPLE ? cnt2 : NSAMPLE;
        __threadfence_block();
    } else {
        __threadfence_block();           // cand[] appends visible to wave
        const int K = ncand;             // == total
        for (int c = l; c < K; c += 64) {
            const int v = cand[c];
            int rnk = 0;
            for (int i = 0; i < K; ++i) rnk += (cand[i] < v) ? 1 : 0;
            if (rnk < NSAMPLE) s_idx[rnk] = v;   // first-32 in index order
        }
        cntv = total < NSAMPLE ? total : NSAMPLE;
        __threadfence_block();
    }

    // fill unfound slots with first index (0 if none)
    if (l < NSAMPLE && l >= cntv) s_idx[l] = (cntv > 0) ? s_idx[0] : 0;
    __threadfence_block();

    if (l == 0) out_cnt[q] = (float)cntv;
    if (l < NSAMPLE) idx_out[q * NSAMPLE + l] = s_idx[l];
}

// ---------------------------------------------------------------------------
// Grouping: pure streaming gather + transpose + coalesced store.
// One wave per query, 4 queries per 256-thr block, per-wave LDS tile.
// ---------------------------------------------------------------------------
__global__ __launch_bounds__(256, 4) void group_kernel(
    const float* __restrict__ xyz,      // (B,N,3)
    const float* __restrict__ new_xyz,  // (B,NPOINT,3)
    const float* __restrict__ ft,       // (B,N,C)
    const int*   __restrict__ idx_in,   // (B*NPOINT, NSAMPLE)
    float* __restrict__ out_feat)       // (B,CH,NPOINT,NSAMPLE)
{
    const int w = threadIdx.x >> 6;
    const int l = threadIdx.x & 63;
    const int q = blockIdx.x * 4 + w;
    const int b = q >> 11;
    const int j = q & (NPOINT - 1);

    __shared__ float tile_s[4][CH * 33];   // stride 33 -> conflict-free
    __shared__ int   sidx_s[4][NSAMPLE];
    float* s_tile = tile_s[w];
    int*   s_idx  = sidx_s[w];

    if (l < NSAMPLE) s_idx[l] = idx_in[q * NSAMPLE + l];
    __threadfence_block();

    // gather 64 feature channels: 16 lanes x 4 slots per pass, float4 rows
    #pragma unroll
    for (int p = 0; p < 8; ++p) {
        const int k  = p * 4 + (l >> 4);         // slot 0..31
        const int c4 = l & 15;                   // float4 within 64 ch
        const int i  = s_idx[k];
        const float4 v = ((const float4*)(ft + ((size_t)b * N + i) * C))[c4];
        const int ch = 3 + c4 * 4;
        s_tile[(ch + 0) * 33 + k] = v.x;
        s_tile[(ch + 1) * 33 + k] = v.y;
        s_tile[(ch + 2) * 33 + k] = v.z;
        s_tile[(ch + 3) * 33 + k] = v.w;
    }
    // xyz channels 0..2 (relative coords)
    if (l < NSAMPLE) {
        const float qx = new_xyz[q * 3 + 0];
        const float qy = new_xyz[q * 3 + 1];
        const float qz = new_xyz[q * 3 + 2];
        const int i = s_idx[l];
        const float* xp = xyz + ((size_t)b * N + i) * 3;
        s_tile[0 * 33 + l] = xp[0] - qx;
        s_tile[1 * 33 + l] = xp[1] - qy;
        s_tile[2 * 33 + l] = xp[2] - qz;
    }
    __threadfence_block();

    // coalesced nontemporal float4 stores (8 lanes cover one 128B line)
    vfloat4* of4 = (vfloat4*)out_feat;
    for (int e4 = l; e4 < CH * 8; e4 += 64) {
        const int ch = e4 >> 3;
        const int k4 = e4 & 7;
        vfloat4 v;
        v.x = s_tile[ch * 33 + k4 * 4 + 0];
        v.y = s_tile[ch * 33 + k4 * 4 + 1];
        v.z = s_tile[ch * 33 + k4 * 4 + 2];
        v.w = s_tile[ch * 33 + k4 * 4 + 3];
        __builtin_nontemporal_store(v, &of4[((size_t)(b * CH + ch) * NPOINT + j) * 8 + k4]);
    }
}

// ---------------------------------------------------------------------------
// Fallback (small workspace): round-2 linear-scan kernel.
// ---------------------------------------------------------------------------
template <bool TRANSPOSED>
__global__ __launch_bounds__(64) void qg_wave_kernel(
    const float* __restrict__ xyz,
    const float* __restrict__ new_xyz,
    const float* __restrict__ feat,
    float* __restrict__ out_cnt,
    float* __restrict__ out_feat)
{
    const int q = blockIdx.x;
    const int b = q >> 11;
    const int j = q & (NPOINT - 1);
    const int l = threadIdx.x;

    __shared__ int   s_idx[NSAMPLE];
    __shared__ float s_tile[CH * 33];

    const float qx = new_xyz[q * 3 + 0];
    const float qy = new_xyz[q * 3 + 1];
    const float qz = new_xyz[q * 3 + 2];
    const float* xb = xyz + (size_t)b * N * 3;

    int cnt = 0;
    for (int base = 0; base < N; base += 64) {
        const int p = base + l;
        const float dx = xb[p * 3 + 0] - qx;
        const float dy = xb[p * 3 + 1] - qy;
        const float dz = xb[p * 3 + 2] - qz;
        const float d2 = dx * dx + dy * dy + dz * dz;
        const bool in = d2 < RADIUS2;
        const unsigned long long m = __ballot(in);
        if (in) {
            const int slot = cnt + __popcll(m & ((1ull << l) - 1ull));
            if (slot < NSAMPLE) s_idx[slot] = p;
        }
        cnt += __popcll(m);
        if (cnt >= NSAMPLE) break;
    }
    if (cnt > NSAMPLE) cnt = NSAMPLE;

    if (l == 0) out_cnt[q] = (float)cnt;
    __syncthreads();
    if (l < NSAMPLE && l >= cnt) s_idx[l] = (cnt > 0) ? s_idx[0] : 0;
    __syncthreads();

    #pragma unroll
    for (int p = 0; p < 8; ++p) {
        const int k  = p * 4 + (l >> 4);
        const int c4 = l & 15;
        const int i  = s_idx[k];
        if (TRANSPOSED) {
            const float4 v = ((const float4*)(feat + ((size_t)b * N + i) * C))[c4];
            const int ch = 3 + c4 * 4;
            s_tile[(ch + 0) * 33 + k] = v.x;
            s_tile[(ch + 1) * 33 + k] = v.y;
            s_tile[(ch + 2) * 33 + k] = v.z;
            s_tile[(ch + 3) * 33 + k] = v.w;
        } else {
            #pragma unroll
            for (int cc = 0; cc < 4; ++cc) {
                const int c = c4 * 4 + cc;
                s_tile[(3 + c) * 33 + k] = feat[((size_t)b * C + c) * N + i];
            }
        }
    }
    if (l < NSAMPLE) {
        const int i = s_idx[l];
        const float* xp = xyz + ((size_t)b * N + i) * 3;
        s_tile[0 * 33 + l] = xp[0] - qx;
        s_tile[1 * 33 + l] = xp[1] - qy;
        s_tile[2 * 33 + l] = xp[2] - qz;
    }
    __syncthreads();

    float4* of4 = (float4*)out_feat;
    for (int e4 = l; e4 < CH * 8; e4 += 64) {
        const int ch = e4 >> 3;
        const int k4 = e4 & 7;
        float4 v;
        v.x = s_tile[ch * 33 + k4 * 4 + 0];
        v.y = s_tile[ch * 33 + k4 * 4 + 1];
        v.z = s_tile[ch * 33 + k4 * 4 + 2];
        v.w = s_tile[ch * 33 + k4 * 4 + 3];
        of4[((size_t)(b * CH + ch) * NPOINT + j) * 8 + k4] = v;
    }
}

extern "C" void kernel_launch(void* const* d_in, const int* in_sizes, int n_in,
                              void* d_out, int out_size, void* d_ws, size_t ws_size,
                              hipStream_t stream) {
    const float* xyz      = (const float*)d_in[0];   // (B,N,3)
    const float* new_xyz  = (const float*)d_in[1];   // (B,NPOINT,3)
    const float* features = (const float*)d_in[2];   // (B,C,N)

    float* out_cnt  = (float*)d_out;                 // B*NPOINT
    float* out_feat = out_cnt + (size_t)B * NPOINT;  // (B,CH,NPOINT,NSAMPLE)

    char* ws = (char*)d_ws;
    const size_t ftB  = (size_t)B * N * C * sizeof(float);          // 16 MB
    const size_t spB  = (size_t)B * N * sizeof(float4);             // 4 MB
    const size_t csB  = (size_t)B * CSTRIDE * sizeof(int);
    const size_t ccB  = (size_t)B * CCSTRIDE * sizeof(int);
    const size_t idxB = (size_t)B * NPOINT * NSAMPLE * sizeof(int); // 1 MB
    const size_t need = ftB + spB + csB + ccB + idxB;

    if (ws_size >= need) {
        float*  ft  = (float*)ws;
        float4* sp  = (float4*)(ws + ftB);
        int*    cs  = (int*)(ws + ftB + spB);
        int*    cc  = (int*)(ws + ftB + spB + csB);
        int*    idx = (int*)(ws + ftB + spB + csB + ccB);
        feat_transpose_zero_kernel<<<dim3(N / 64, B), 256, 0, stream>>>(features, ft, cc);
        count_kernel<<<B * N / 256, 256, 0, stream>>>(xyz, cc);
        prefix_kernel<<<B, 1024, 0, stream>>>(cc, cs);
        scatter_kernel<<<B * N / 256, 256, 0, stream>>>(xyz, cc, sp);
        ballquery_kernel<<<B * NPOINT / 4, 256, 0, stream>>>(xyz, new_xyz, cs, sp,
                                                             out_cnt, idx);
        group_kernel<<<B * NPOINT / 4, 256, 0, stream>>>(xyz, new_xyz, ft, idx,
                                                         out_feat);
    } else if (ws_size >= ftB) {
        float* ft = (float*)ws;
        feat_transpose_zero_kernel<<<dim3(N / 64, B), 256, 0, stream>>>(
            features, ft, (int*)(ws + ftB - (size_t)B * CCSTRIDE * sizeof(int)));
        qg_wave_kernel<true><<<B * NPOINT, 64, 0, stream>>>(xyz, new_xyz, ft,
                                                            out_cnt, out_feat);
    } else {
        qg_wave_kernel<false><<<B * NPOINT, 64, 0, stream>>>(xyz, new_xyz, features,
                                                             out_cnt, out_feat);
    }
}